// Round 1
// baseline (172.373 us; speedup 1.0000x reference)
//
#include <hip/hip_runtime.h>
#include <hip/hip_cooperative_groups.h>

namespace cg = cooperative_groups;

constexpr int T_TOK = 8192;
constexpr int H_DIM = 2048;
constexpr int E_NUM = 8;
constexpr int L_DIM = 16;
constexpr int NBLK2 = 32;   // blocks in sinkhorn kernel; NBLK2*256 == T_TOK

// workspace layout (float offsets)
constexpr size_t WS_COST = 0;                         // T*16
constexpr size_t WS_D0   = (size_t)T_TOK * L_DIM;     // T
constexpr size_t WS_D1   = WS_D0 + T_TOK;             // 16
constexpr size_t WS_PART = WS_D1 + L_DIM;             // 2 * NBLK2 * 16

// ---------------- Kernel 1: grouped logits + exp -> cost ----------------
// block = 256 thr, 16 tokens/block, 16 threads per token split over H.
__global__ __launch_bounds__(256) void k_logits(const float* __restrict__ x,
                                                const float* __restrict__ w1,
                                                const int* __restrict__ tpe,
                                                float* __restrict__ cost) {
    const int tid = threadIdx.x;
    const int tt  = tid >> 4;          // token within block (0..15)
    const int hp  = tid & 15;          // h-partition (0..15)
    const int t   = blockIdx.x * 16 + tt;

    // expert id from prefix sums of tokens_per_expert (tokens contiguous per expert)
    int e = 0;
    {
        int accum = 0;
        #pragma unroll
        for (int i = 0; i < E_NUM - 1; ++i) {
            accum += tpe[i];
            e += (t >= accum) ? 1 : 0;
        }
    }

    const float* xr = x  + (size_t)t * H_DIM;
    const float* wr = w1 + (size_t)e * H_DIM * L_DIM;

    float a[L_DIM];
    #pragma unroll
    for (int l = 0; l < L_DIM; ++l) a[l] = 0.f;

    // each thread covers h = k*64 + hp*4 .. +3, k = 0..31
    #pragma unroll 2
    for (int k = 0; k < H_DIM / 64; ++k) {
        const int h0 = k * 64 + hp * 4;
        const float4 xv = *reinterpret_cast<const float4*>(xr + h0);
        const float xs[4] = {xv.x, xv.y, xv.z, xv.w};
        #pragma unroll
        for (int j = 0; j < 4; ++j) {
            const float4* wrow = reinterpret_cast<const float4*>(wr + (size_t)(h0 + j) * L_DIM);
            #pragma unroll
            for (int q = 0; q < 4; ++q) {
                const float4 wv = wrow[q];
                a[q * 4 + 0] += xs[j] * wv.x;
                a[q * 4 + 1] += xs[j] * wv.y;
                a[q * 4 + 2] += xs[j] * wv.z;
                a[q * 4 + 3] += xs[j] * wv.w;
            }
        }
    }

    // reduce 16 h-partials per (token, l) via LDS transpose
    __shared__ float lds[16][16][17];   // [token][hp][l], pad to dodge conflicts
    #pragma unroll
    for (int l = 0; l < L_DIM; ++l) lds[tt][hp][l] = a[l];
    __syncthreads();

    float s = 0.f;
    #pragma unroll
    for (int p = 0; p < 16; ++p) s += lds[tt][p][hp];   // deterministic order
    cost[(size_t)t * L_DIM + hp] = expf(s);
}

// ---------------- Kernel 2: Sinkhorn to convergence (cooperative) ----------------
// one thread = one row (16 cost values held in VGPRs). One grid.sync per iteration.
// Deterministic cross-block reduction: each block writes its 16 partials to a
// parity-double-buffered slab; after sync every block re-sums all 32 partials
// in a fixed order (bitwise identical across blocks and across replays).
__global__ __launch_bounds__(256) void k_sinkhorn(float* __restrict__ ws) {
    cg::grid_group grid = cg::this_grid();

    const float* cost = ws + WS_COST;
    float* d0ws = ws + WS_D0;
    float* d1ws = ws + WS_D1;
    float* part = ws + WS_PART;

    const int t    = blockIdx.x * blockDim.x + threadIdx.x;   // row id
    const int wv   = threadIdx.x >> 6;
    const int lane = threadIdx.x & 63;

    float c[16];
    {
        const float4* cr = reinterpret_cast<const float4*>(cost + (size_t)t * 16);
        const float4 c0 = cr[0], c1 = cr[1], c2 = cr[2], c3 = cr[3];
        c[0]=c0.x; c[1]=c0.y; c[2]=c0.z; c[3]=c0.w;
        c[4]=c1.x; c[5]=c1.y; c[6]=c1.z; c[7]=c1.w;
        c[8]=c2.x; c[9]=c2.y; c[10]=c2.z; c[11]=c2.w;
        c[12]=c3.x; c[13]=c3.y; c[14]=c3.z; c[15]=c3.w;
    }

    float d1[16];
    #pragma unroll
    for (int l = 0; l < 16; ++l) d1[l] = 1.f;

    __shared__ float s_part[4][16];
    __shared__ float s_d1n[16];

    float d0n = 0.f;
    float err = 1e9f;
    int it = 0;

    do {
        // d0n = (1/T) / (cost @ d1 + eps)
        float s = 0.f;
        #pragma unroll
        for (int l = 0; l < 16; ++l) s += c[l] * d1[l];
        d0n = (1.f / (float)T_TOK) / (s + 1e-8f);

        // partial column sums of d0n * cost
        float con[16];
        #pragma unroll
        for (int l = 0; l < 16; ++l) con[l] = d0n * c[l];
        #pragma unroll
        for (int m = 1; m < 64; m <<= 1) {
            #pragma unroll
            for (int l = 0; l < 16; ++l) con[l] += __shfl_xor(con[l], m, 64);
        }
        if (lane == 0) {
            #pragma unroll
            for (int l = 0; l < 16; ++l) s_part[wv][l] = con[l];
        }
        __syncthreads();

        const int p = it & 1;
        if (threadIdx.x < 16) {
            const float bs = s_part[0][threadIdx.x] + s_part[1][threadIdx.x]
                           + s_part[2][threadIdx.x] + s_part[3][threadIdx.x];
            part[(size_t)p * (NBLK2 * 16) + (size_t)blockIdx.x * 16 + threadIdx.x] = bs;
        }

        grid.sync();

        if (threadIdx.x < 16) {
            float tot = 0.f;
            #pragma unroll 4
            for (int b = 0; b < NBLK2; ++b)
                tot += part[(size_t)p * (NBLK2 * 16) + (size_t)b * 16 + threadIdx.x];
            s_d1n[threadIdx.x] = (1.f / (float)L_DIM) / (tot + 1e-8f);
        }
        __syncthreads();

        float esum = 0.f;
        #pragma unroll
        for (int l = 0; l < 16; ++l) {
            const float nv = s_d1n[l];
            esum += fabsf(d1[l] - nv);
            d1[l] = nv;
        }
        err = esum * (1.f / 16.f);
        ++it;
    } while (err > 1e-4f && it < 512);

    d0ws[t] = d0n;   // final d0 (computed from previous d1, exactly as reference)
    if (blockIdx.x == 0 && threadIdx.x < 16) d1ws[threadIdx.x] = s_d1n[threadIdx.x];
}

// ---------------- Kernel 3: top-2 of d1*cost*d0, softmax-gather ----------------
__global__ __launch_bounds__(256) void k_final(const float* __restrict__ ws,
                                               float* __restrict__ out) {
    const float* cost = ws + WS_COST;
    const float* d0ws = ws + WS_D0;
    const float* d1ws = ws + WS_D1;

    const int t = blockIdx.x * blockDim.x + threadIdx.x;

    float c[16];
    {
        const float4* cr = reinterpret_cast<const float4*>(cost + (size_t)t * 16);
        const float4 c0 = cr[0], c1 = cr[1], c2 = cr[2], c3 = cr[3];
        c[0]=c0.x; c[1]=c0.y; c[2]=c0.z; c[3]=c0.w;
        c[4]=c1.x; c[5]=c1.y; c[6]=c1.z; c[7]=c1.w;
        c[8]=c2.x; c[9]=c2.y; c[10]=c2.z; c[11]=c2.w;
        c[12]=c3.x; c[13]=c3.y; c[14]=c3.z; c[15]=c3.w;
    }
    const float d0v = d0ws[t];

    float v1 = -__builtin_inff(), v2 = -__builtin_inff();
    float a1 = 0.f, a2 = 0.f;     // cost values of the selected entries
    int   i1 = 0, i2 = 0;
    float ssum = 0.f;
    #pragma unroll
    for (int l = 0; l < 16; ++l) {
        ssum += c[l];
        const float nv = (d1ws[l] * c[l]) * d0v;   // same op order as reference
        if (nv > v1) { v2 = v1; i2 = i1; a2 = a1; v1 = nv; i1 = l; a1 = c[l]; }
        else if (nv > v2) { v2 = nv; i2 = l; a2 = c[l]; }
    }
    const float sc1 = a1 / ssum;   // softmax(logits)[i] == cost[i]/sum(cost)
    const float sc2 = a2 / ssum;

    out[(size_t)t * 2 + 0] = sc1;
    out[(size_t)t * 2 + 1] = sc2;
    out[(size_t)2 * T_TOK + (size_t)t * 2 + 0] = (float)i1;
    out[(size_t)2 * T_TOK + (size_t)t * 2 + 1] = (float)i2;
}

extern "C" void kernel_launch(void* const* d_in, const int* in_sizes, int n_in,
                              void* d_out, int out_size, void* d_ws, size_t ws_size,
                              hipStream_t stream) {
    const float* x   = (const float*)d_in[0];
    const float* w1  = (const float*)d_in[1];
    const int*   tpe = (const int*)d_in[2];
    float* ws  = (float*)d_ws;
    float* out = (float*)d_out;

    // K1: logits + exp
    k_logits<<<dim3(T_TOK / 16), dim3(256), 0, stream>>>(x, w1, tpe, ws);

    // K2: sinkhorn (cooperative — grid-wide sync each iteration)
    {
        void* args[] = { (void*)&ws };
        hipLaunchCooperativeKernel((void*)k_sinkhorn, dim3(NBLK2), dim3(256),
                                   args, 0, stream);
    }

    // K3: top-2 + softmax gather
    k_final<<<dim3(T_TOK / 256), dim3(256), 0, stream>>>(ws, out);
}

// Round 2
// 103.369 us; speedup vs baseline: 1.6676x; 1.6676x over previous
//
#include <hip/hip_runtime.h>
#include <hip/hip_cooperative_groups.h>

namespace cg = cooperative_groups;

constexpr int T_TOK = 8192;
constexpr int H_DIM = 2048;
constexpr int E_NUM = 8;
constexpr int L_DIM = 16;
constexpr int NBLK2 = 32;   // blocks in sinkhorn kernel; NBLK2*256 == T_TOK

// logits kernel geometry
constexpr int NSB    = 8;    // slice-blocks per token-set (partials in ws)
constexpr int HSLICE = 64;   // h per wave-slice; 8 sb * 4 waves * 64 = 2048 ✓

// workspace layout (float offsets)
constexpr size_t WS_COST = 0;                         // T*16
constexpr size_t WS_D0   = (size_t)T_TOK * L_DIM;     // T
constexpr size_t WS_D1   = WS_D0 + T_TOK;             // 16
constexpr size_t WS_PART = WS_D1 + L_DIM;             // 2 * NBLK2 * 16
constexpr size_t WS_PB   = WS_PART + 2 * NBLK2 * 16;  // NSB * T * 16

// ---------------- Kernel 1a: grouped logits partials ----------------
// token-per-lane; wave-uniform w rows -> scalar loads. Each wave covers one
// 64-h slice of 64 tokens; 4 waves/block reduce in LDS; 8 slice-blocks emit
// partials to ws.
__global__ __launch_bounds__(256) void k1a(const float* __restrict__ x,
                                           const float* __restrict__ w1,
                                           const int* __restrict__ tpe,
                                           float* __restrict__ pb) {
    const int wv   = threadIdx.x >> 6;
    const int lane = threadIdx.x & 63;
    const int sb   = blockIdx.x & (NSB - 1);   // slice-block 0..7
    const int tset = blockIdx.x >> 3;          // token-set 0..127
    const int t    = tset * 64 + lane;
    const int h0   = (sb * 4 + wv) * HSLICE;   // this wave's h base

    // expert id (wave-uniform for the harness's 1024-per-expert layout)
    int e = 0;
    {
        int accum = 0;
        #pragma unroll
        for (int i = 0; i < E_NUM - 1; ++i) {
            accum += tpe[i];
            e += (t >= accum) ? 1 : 0;
        }
    }
    const int e0 = __builtin_amdgcn_readfirstlane(e);
    const float* __restrict__ wrow = w1 + ((size_t)e0 * H_DIM + h0) * L_DIM; // uniform ptr

    // prefetch the lane's whole x slice: 16 independent float4 loads in flight
    const float4* __restrict__ xp =
        reinterpret_cast<const float4*>(x + (size_t)t * H_DIM + h0);
    float4 xs[16];
    #pragma unroll
    for (int i = 0; i < 16; ++i) xs[i] = xp[i];

    float acc[16];
    #pragma unroll
    for (int l = 0; l < 16; ++l) acc[l] = 0.f;

    #pragma unroll
    for (int i = 0; i < 16; ++i) {
        const float xv[4] = {xs[i].x, xs[i].y, xs[i].z, xs[i].w};
        #pragma unroll
        for (int j = 0; j < 4; ++j) {
            const int h = i * 4 + j;
            // wrow[h*16 + l] is wave-uniform -> s_load through constant cache
            #pragma unroll
            for (int l = 0; l < 16; ++l)
                acc[l] += xv[j] * wrow[h * 16 + l];
        }
    }

    // in-block reduction across the 4 waves (4 h-slices of same tokens)
    __shared__ float red[4][64][17];   // pad 17: conflict-free b32
    #pragma unroll
    for (int l = 0; l < 16; ++l) red[wv][lane][l] = acc[l];
    __syncthreads();

    // 64 tokens * 16 L = 1024 outputs; 256 threads do 4 each, coalesced store
    #pragma unroll
    for (int i = 0; i < 4; ++i) {
        const int p   = threadIdx.x + i * 256;   // 0..1023
        const int tok = p >> 4;
        const int l   = p & 15;
        const float s = red[0][tok][l] + red[1][tok][l]
                      + red[2][tok][l] + red[3][tok][l];
        pb[(size_t)sb * (T_TOK * L_DIM) + (size_t)tset * 1024 + p] = s;
    }
}

// ---------------- Kernel 1b: sum slice-block partials, exp -> cost ----------------
__global__ __launch_bounds__(256) void k1b(const float* __restrict__ pb,
                                           float* __restrict__ cost) {
    const int o = blockIdx.x * 256 + threadIdx.x;   // 0 .. T*16-1
    float s = 0.f;
    #pragma unroll
    for (int b = 0; b < NSB; ++b)
        s += pb[(size_t)b * (T_TOK * L_DIM) + o];
    cost[o] = expf(s);
}

// ---------------- Kernel 2: Sinkhorn to convergence (cooperative) ----------------
// one thread = one row (16 cost values in VGPRs). One grid.sync per iteration.
// Deterministic cross-block reduction via parity-double-buffered partial slab.
__global__ __launch_bounds__(256) void k_sinkhorn(float* __restrict__ ws) {
    cg::grid_group grid = cg::this_grid();

    const float* cost = ws + WS_COST;
    float* d0ws = ws + WS_D0;
    float* d1ws = ws + WS_D1;
    float* part = ws + WS_PART;

    const int t    = blockIdx.x * blockDim.x + threadIdx.x;   // row id
    const int wv   = threadIdx.x >> 6;
    const int lane = threadIdx.x & 63;

    float c[16];
    {
        const float4* cr = reinterpret_cast<const float4*>(cost + (size_t)t * 16);
        const float4 c0 = cr[0], c1 = cr[1], c2 = cr[2], c3 = cr[3];
        c[0]=c0.x; c[1]=c0.y; c[2]=c0.z; c[3]=c0.w;
        c[4]=c1.x; c[5]=c1.y; c[6]=c1.z; c[7]=c1.w;
        c[8]=c2.x; c[9]=c2.y; c[10]=c2.z; c[11]=c2.w;
        c[12]=c3.x; c[13]=c3.y; c[14]=c3.z; c[15]=c3.w;
    }

    float d1[16];
    #pragma unroll
    for (int l = 0; l < 16; ++l) d1[l] = 1.f;

    __shared__ float s_part[4][16];
    __shared__ float s_d1n[16];

    float d0n = 0.f;
    float err = 1e9f;
    int it = 0;

    do {
        // d0n = (1/T) / (cost @ d1 + eps)
        float s = 0.f;
        #pragma unroll
        for (int l = 0; l < 16; ++l) s += c[l] * d1[l];
        d0n = (1.f / (float)T_TOK) / (s + 1e-8f);

        // partial column sums of d0n * cost
        float con[16];
        #pragma unroll
        for (int l = 0; l < 16; ++l) con[l] = d0n * c[l];
        #pragma unroll
        for (int m = 1; m < 64; m <<= 1) {
            #pragma unroll
            for (int l = 0; l < 16; ++l) con[l] += __shfl_xor(con[l], m, 64);
        }
        if (lane == 0) {
            #pragma unroll
            for (int l = 0; l < 16; ++l) s_part[wv][l] = con[l];
        }
        __syncthreads();

        const int p = it & 1;
        if (threadIdx.x < 16) {
            const float bs = s_part[0][threadIdx.x] + s_part[1][threadIdx.x]
                           + s_part[2][threadIdx.x] + s_part[3][threadIdx.x];
            part[(size_t)p * (NBLK2 * 16) + (size_t)blockIdx.x * 16 + threadIdx.x] = bs;
        }

        grid.sync();

        if (threadIdx.x < 16) {
            float tot = 0.f;
            #pragma unroll 4
            for (int b = 0; b < NBLK2; ++b)
                tot += part[(size_t)p * (NBLK2 * 16) + (size_t)b * 16 + threadIdx.x];
            s_d1n[threadIdx.x] = (1.f / (float)L_DIM) / (tot + 1e-8f);
        }
        __syncthreads();

        float esum = 0.f;
        #pragma unroll
        for (int l = 0; l < 16; ++l) {
            const float nv = s_d1n[l];
            esum += fabsf(d1[l] - nv);
            d1[l] = nv;
        }
        err = esum * (1.f / 16.f);
        ++it;
    } while (err > 1e-4f && it < 512);

    d0ws[t] = d0n;   // final d0 (from previous d1, exactly as reference)
    if (blockIdx.x == 0 && threadIdx.x < 16) d1ws[threadIdx.x] = s_d1n[threadIdx.x];
}

// ---------------- Kernel 3: top-2 of d1*cost*d0, softmax-gather ----------------
__global__ __launch_bounds__(256) void k_final(const float* __restrict__ ws,
                                               float* __restrict__ out) {
    const float* cost = ws + WS_COST;
    const float* d0ws = ws + WS_D0;
    const float* d1ws = ws + WS_D1;

    const int t = blockIdx.x * blockDim.x + threadIdx.x;

    float c[16];
    {
        const float4* cr = reinterpret_cast<const float4*>(cost + (size_t)t * 16);
        const float4 c0 = cr[0], c1 = cr[1], c2 = cr[2], c3 = cr[3];
        c[0]=c0.x; c[1]=c0.y; c[2]=c0.z; c[3]=c0.w;
        c[4]=c1.x; c[5]=c1.y; c[6]=c1.z; c[7]=c1.w;
        c[8]=c2.x; c[9]=c2.y; c[10]=c2.z; c[11]=c2.w;
        c[12]=c3.x; c[13]=c3.y; c[14]=c3.z; c[15]=c3.w;
    }
    const float d0v = d0ws[t];

    float v1 = -__builtin_inff(), v2 = -__builtin_inff();
    float a1 = 0.f, a2 = 0.f;
    int   i1 = 0, i2 = 0;
    float ssum = 0.f;
    #pragma unroll
    for (int l = 0; l < 16; ++l) {
        ssum += c[l];
        const float nv = (d1ws[l] * c[l]) * d0v;   // same op order as reference
        if (nv > v1) { v2 = v1; i2 = i1; a2 = a1; v1 = nv; i1 = l; a1 = c[l]; }
        else if (nv > v2) { v2 = nv; i2 = l; a2 = c[l]; }
    }
    const float sc1 = a1 / ssum;   // softmax(logits)[i] == cost[i]/sum(cost)
    const float sc2 = a2 / ssum;

    out[(size_t)t * 2 + 0] = sc1;
    out[(size_t)t * 2 + 1] = sc2;
    out[(size_t)2 * T_TOK + (size_t)t * 2 + 0] = (float)i1;
    out[(size_t)2 * T_TOK + (size_t)t * 2 + 1] = (float)i2;
}

extern "C" void kernel_launch(void* const* d_in, const int* in_sizes, int n_in,
                              void* d_out, int out_size, void* d_ws, size_t ws_size,
                              hipStream_t stream) {
    const float* x   = (const float*)d_in[0];
    const float* w1  = (const float*)d_in[1];
    const int*   tpe = (const int*)d_in[2];
    float* ws  = (float*)d_ws;
    float* out = (float*)d_out;

    // K1: logits partials (1024 blocks = 4096 waves) + reduce/exp
    k1a<<<dim3(128 * NSB), dim3(256), 0, stream>>>(x, w1, tpe, ws + WS_PB);
    k1b<<<dim3(T_TOK * L_DIM / 256), dim3(256), 0, stream>>>(ws + WS_PB, ws + WS_COST);

    // K2: sinkhorn (cooperative — grid-wide sync each iteration)
    {
        void* args[] = { (void*)&ws };
        hipLaunchCooperativeKernel((void*)k_sinkhorn, dim3(NBLK2), dim3(256),
                                   args, 0, stream);
    }

    // K3: top-2 + softmax gather
    k_final<<<dim3(T_TOK / 256), dim3(256), 0, stream>>>(ws, out);
}

// Round 3
// 75.398 us; speedup vs baseline: 2.2862x; 1.3710x over previous
//
#include <hip/hip_runtime.h>
#include <hip/hip_cooperative_groups.h>

namespace cg = cooperative_groups;

constexpr int T_TOK = 8192;
constexpr int H_DIM = 2048;
constexpr int E_NUM = 8;
constexpr int L_DIM = 16;
constexpr int NBLK2 = 32;   // blocks in sinkhorn kernel; NBLK2*256 == T_TOK

// logits kernel geometry
constexpr int NSB    = 8;    // slice-blocks per token-set
constexpr int HSLICE = 64;   // h per wave; 8 sb * 4 waves * 64 = 2048

// workspace layout (float offsets)
constexpr size_t WS_COST = 0;                         // T*16
constexpr size_t WS_D0   = (size_t)T_TOK * L_DIM;     // T
constexpr size_t WS_D1   = WS_D0 + T_TOK;             // 16
constexpr size_t WS_PART = WS_D1 + L_DIM;             // 2 * NBLK2 * 16
constexpr size_t WS_PB   = WS_PART + 2 * NBLK2 * 16;  // NSB * T * 16

// ---------------- Kernel 1: grouped logits partials ----------------
// token-per-lane; w broadcast from LDS (staged once per block). Each wave
// covers one 64-h slice of 64 tokens; 4 waves/block reduce in LDS; 8
// slice-blocks emit partials to ws.
__global__ __launch_bounds__(256) void k1a(const float* __restrict__ x,
                                           const float* __restrict__ w1,
                                           const int* __restrict__ tpe,
                                           float* __restrict__ pb) {
    const int tid  = threadIdx.x;
    const int wv   = tid >> 6;
    const int lane = tid & 63;
    const int sb   = blockIdx.x & (NSB - 1);   // slice-block 0..7
    const int tset = blockIdx.x >> 3;          // token-set 0..127
    const int t    = tset * 64 + lane;
    const int h0   = sb * 256 + wv * HSLICE;   // this wave's h base

    // union LDS: phase 1 = w slice [256][16]; phase 2 = red [4][64][17]
    __shared__ float smem[4352];

    // expert id (uniform across the 64-token set for the harness layout)
    int e = 0;
    {
        int accum = 0;
        #pragma unroll
        for (int i = 0; i < E_NUM - 1; ++i) {
            accum += tpe[i];
            e += (t >= accum) ? 1 : 0;
        }
    }
    const int e0 = __builtin_amdgcn_readfirstlane(e);

    // ---- stage w[e][sb*256 .. +256)[0..16) -> LDS (16 KB), coalesced ----
    {
        const float4* wsrc =
            reinterpret_cast<const float4*>(w1 + ((size_t)e0 * H_DIM + sb * 256) * L_DIM);
        #pragma unroll
        for (int i = 0; i < 4; ++i) {
            const int idx = i * 256 + tid;              // float4 index 0..1023
            *reinterpret_cast<float4*>(&smem[idx * 4]) = wsrc[idx];
        }
    }

    // ---- prefetch the lane's x slice: 16 independent float4 loads ----
    const float4* __restrict__ xp =
        reinterpret_cast<const float4*>(x + (size_t)t * H_DIM + h0);
    float4 xs[16];
    #pragma unroll
    for (int i = 0; i < 16; ++i) xs[i] = xp[i];

    __syncthreads();

    float acc[16];
    #pragma unroll
    for (int l = 0; l < 16; ++l) acc[l] = 0.f;

    const float* wl = &smem[(size_t)wv * HSLICE * 16];   // this wave's 64 h rows
    #pragma unroll
    for (int i = 0; i < 16; ++i) {
        const float xv[4] = {xs[i].x, xs[i].y, xs[i].z, xs[i].w};
        #pragma unroll
        for (int j = 0; j < 4; ++j) {
            const int h = i * 4 + j;
            // wave-uniform LDS address -> broadcast ds_read_b128, no conflicts
            const float4* wrow = reinterpret_cast<const float4*>(wl + h * 16);
            #pragma unroll
            for (int q = 0; q < 4; ++q) {
                const float4 wv4 = wrow[q];
                acc[q * 4 + 0] += xv[j] * wv4.x;
                acc[q * 4 + 1] += xv[j] * wv4.y;
                acc[q * 4 + 2] += xv[j] * wv4.z;
                acc[q * 4 + 3] += xv[j] * wv4.w;
            }
        }
    }

    // ---- in-block reduction across the 4 waves ----
    __syncthreads();   // everyone done reading w; reuse smem as red[4][64][17]
    #pragma unroll
    for (int l = 0; l < 16; ++l)
        smem[((size_t)wv * 64 + lane) * 17 + l] = acc[l];
    __syncthreads();

    // 64 tokens * 16 L = 1024 outputs; 256 threads do 4 each, coalesced store
    #pragma unroll
    for (int i = 0; i < 4; ++i) {
        const int p   = tid + i * 256;   // 0..1023
        const int tok = p >> 4;
        const int l   = p & 15;
        const float s = smem[(0 * 64 + tok) * 17 + l] + smem[(1 * 64 + tok) * 17 + l]
                      + smem[(2 * 64 + tok) * 17 + l] + smem[(3 * 64 + tok) * 17 + l];
        pb[(size_t)sb * (T_TOK * L_DIM) + (size_t)tset * 1024 + p] = s;
    }
}

// ---------------- Kernel 2: Sinkhorn (cooperative), pb-reduce fused ----------------
// one thread = one row (16 cost values in VGPRs). One grid.sync per iteration.
// Deterministic cross-block reduction via parity-double-buffered partial slab.
__global__ __launch_bounds__(256) void k_sinkhorn(float* __restrict__ ws) {
    cg::grid_group grid = cg::this_grid();

    float* costw = ws + WS_COST;
    float* d0ws  = ws + WS_D0;
    float* d1ws  = ws + WS_D1;
    float* part  = ws + WS_PART;
    const float* pb = ws + WS_PB;

    const int t    = blockIdx.x * blockDim.x + threadIdx.x;   // row id
    const int wv   = threadIdx.x >> 6;
    const int lane = threadIdx.x & 63;

    // fused k1b: sum slice-block partials, exp -> c[]; write cost for k3
    float c[16];
    {
        float4 a0 = {0, 0, 0, 0}, a1 = {0, 0, 0, 0}, a2 = {0, 0, 0, 0}, a3 = {0, 0, 0, 0};
        #pragma unroll
        for (int b = 0; b < NSB; ++b) {
            const float4* pr =
                reinterpret_cast<const float4*>(pb + (size_t)b * (T_TOK * L_DIM) + (size_t)t * 16);
            const float4 p0 = pr[0], p1 = pr[1], p2 = pr[2], p3 = pr[3];
            a0.x += p0.x; a0.y += p0.y; a0.z += p0.z; a0.w += p0.w;
            a1.x += p1.x; a1.y += p1.y; a1.z += p1.z; a1.w += p1.w;
            a2.x += p2.x; a2.y += p2.y; a2.z += p2.z; a2.w += p2.w;
            a3.x += p3.x; a3.y += p3.y; a3.z += p3.z; a3.w += p3.w;
        }
        const float sv[16] = {a0.x, a0.y, a0.z, a0.w, a1.x, a1.y, a1.z, a1.w,
                              a2.x, a2.y, a2.z, a2.w, a3.x, a3.y, a3.z, a3.w};
        #pragma unroll
        for (int l = 0; l < 16; ++l) c[l] = expf(sv[l]);
        float4* cw = reinterpret_cast<float4*>(costw + (size_t)t * 16);
        cw[0] = make_float4(c[0], c[1], c[2], c[3]);
        cw[1] = make_float4(c[4], c[5], c[6], c[7]);
        cw[2] = make_float4(c[8], c[9], c[10], c[11]);
        cw[3] = make_float4(c[12], c[13], c[14], c[15]);
    }

    float d1[16];
    #pragma unroll
    for (int l = 0; l < 16; ++l) d1[l] = 1.f;

    __shared__ float s_part[4][16];
    __shared__ float s_d1n[16];

    float d0n = 0.f;
    float err = 1e9f;
    int it = 0;

    do {
        // d0n = (1/T) / (cost @ d1 + eps)
        float s = 0.f;
        #pragma unroll
        for (int l = 0; l < 16; ++l) s += c[l] * d1[l];
        d0n = (1.f / (float)T_TOK) / (s + 1e-8f);

        // partial column sums of d0n * cost
        float con[16];
        #pragma unroll
        for (int l = 0; l < 16; ++l) con[l] = d0n * c[l];
        #pragma unroll
        for (int m = 1; m < 64; m <<= 1) {
            #pragma unroll
            for (int l = 0; l < 16; ++l) con[l] += __shfl_xor(con[l], m, 64);
        }
        if (lane == 0) {
            #pragma unroll
            for (int l = 0; l < 16; ++l) s_part[wv][l] = con[l];
        }
        __syncthreads();

        const int p = it & 1;
        if (threadIdx.x < 16) {
            const float bs = s_part[0][threadIdx.x] + s_part[1][threadIdx.x]
                           + s_part[2][threadIdx.x] + s_part[3][threadIdx.x];
            part[(size_t)p * (NBLK2 * 16) + (size_t)blockIdx.x * 16 + threadIdx.x] = bs;
        }

        grid.sync();

        if (threadIdx.x < 16) {
            float tot = 0.f;
            #pragma unroll 4
            for (int b = 0; b < NBLK2; ++b)
                tot += part[(size_t)p * (NBLK2 * 16) + (size_t)b * 16 + threadIdx.x];
            s_d1n[threadIdx.x] = (1.f / (float)L_DIM) / (tot + 1e-8f);
        }
        __syncthreads();

        float esum = 0.f;
        #pragma unroll
        for (int l = 0; l < 16; ++l) {
            const float nv = s_d1n[l];
            esum += fabsf(d1[l] - nv);
            d1[l] = nv;
        }
        err = esum * (1.f / 16.f);
        ++it;
    } while (err > 1e-4f && it < 512);

    d0ws[t] = d0n;   // final d0 (from previous d1, exactly as reference)
    if (blockIdx.x == 0 && threadIdx.x < 16) d1ws[threadIdx.x] = s_d1n[threadIdx.x];
}

// ---------------- Kernel 3: top-2 of d1*cost*d0, softmax-gather ----------------
__global__ __launch_bounds__(256) void k_final(const float* __restrict__ ws,
                                               float* __restrict__ out) {
    const float* cost = ws + WS_COST;
    const float* d0ws = ws + WS_D0;
    const float* d1ws = ws + WS_D1;

    const int t = blockIdx.x * blockDim.x + threadIdx.x;

    float c[16];
    {
        const float4* cr = reinterpret_cast<const float4*>(cost + (size_t)t * 16);
        const float4 c0 = cr[0], c1 = cr[1], c2 = cr[2], c3 = cr[3];
        c[0]=c0.x; c[1]=c0.y; c[2]=c0.z; c[3]=c0.w;
        c[4]=c1.x; c[5]=c1.y; c[6]=c1.z; c[7]=c1.w;
        c[8]=c2.x; c[9]=c2.y; c[10]=c2.z; c[11]=c2.w;
        c[12]=c3.x; c[13]=c3.y; c[14]=c3.z; c[15]=c3.w;
    }
    const float d0v = d0ws[t];

    float v1 = -__builtin_inff(), v2 = -__builtin_inff();
    float a1 = 0.f, a2 = 0.f;
    int   i1 = 0, i2 = 0;
    float ssum = 0.f;
    #pragma unroll
    for (int l = 0; l < 16; ++l) {
        ssum += c[l];
        const float nv = (d1ws[l] * c[l]) * d0v;   // same op order as reference
        if (nv > v1) { v2 = v1; i2 = i1; a2 = a1; v1 = nv; i1 = l; a1 = c[l]; }
        else if (nv > v2) { v2 = nv; i2 = l; a2 = c[l]; }
    }
    const float sc1 = a1 / ssum;   // softmax(logits)[i] == cost[i]/sum(cost)
    const float sc2 = a2 / ssum;

    out[(size_t)t * 2 + 0] = sc1;
    out[(size_t)t * 2 + 1] = sc2;
    out[(size_t)2 * T_TOK + (size_t)t * 2 + 0] = (float)i1;
    out[(size_t)2 * T_TOK + (size_t)t * 2 + 1] = (float)i2;
}

extern "C" void kernel_launch(void* const* d_in, const int* in_sizes, int n_in,
                              void* d_out, int out_size, void* d_ws, size_t ws_size,
                              hipStream_t stream) {
    const float* x   = (const float*)d_in[0];
    const float* w1  = (const float*)d_in[1];
    const int*   tpe = (const int*)d_in[2];
    float* ws  = (float*)d_ws;
    float* out = (float*)d_out;

    // K1: logits partials (1024 blocks = 4096 waves)
    k1a<<<dim3(128 * NSB), dim3(256), 0, stream>>>(x, w1, tpe, ws + WS_PB);

    // K2: pb-reduce + exp fused, then sinkhorn (cooperative)
    {
        void* args[] = { (void*)&ws };
        hipLaunchCooperativeKernel((void*)k_sinkhorn, dim3(NBLK2), dim3(256),
                                   args, 0, stream);
    }

    // K3: top-2 + softmax gather
    k_final<<<dim3(T_TOK / 256), dim3(256), 0, stream>>>(ws, out);
}